// Round 2
// baseline (562.174 us; speedup 1.0000x reference)
//
#include <hip/hip_runtime.h>
#include <hip/hip_bf16.h>
#include <math.h>

// Problem constants: B=128, C=64, H=W=64, R=3 -> 49 offsets.

__device__ __forceinline__ float bf2f(__hip_bfloat16 h){ return __bfloat162float(h); }
__device__ __forceinline__ float geluf(float x){ return 0.5f*x*(1.0f+erff(x*0.70710678118654752f)); }

// ---------------------------------------------------------------------------
// Kernel A: per-row (h) tile: 64x64 channel projection GEMM for rubin & vis,
// L2-normalize over channels, write bf16 normalized fields, energy*gauss (t),
// per-batch t-sum (S), and gaussian pools of the RAW features.
// Block: 256 threads = 16 (o_t) x 16 (p_t), each thread owns 4 o x 4 w.
// ---------------------------------------------------------------------------
__global__ __launch_bounds__(256) void proj_kernel(
    const float* __restrict__ rubin, const float* __restrict__ vis,
    const float* __restrict__ Wr, const float* __restrict__ Wv,
    __hip_bfloat16* __restrict__ rn, __hip_bfloat16* __restrict__ vn,
    float* __restrict__ t_out, float* __restrict__ S_out,
    float* __restrict__ r_pool, float* __restrict__ v_pool,
    float inv_gsum)
{
    __shared__ float WtA[64][68];   // transposed weights [c][o], padded
    __shared__ float WtB[64][68];
    __shared__ float Xs[64][68];    // raw feature tile [c][w] for this row
    __shared__ float red[16][64];   // norm partial sums [o_t][w]
    __shared__ float redS[16];
    __shared__ float gxs[64];       // exp(-2*x^2) per column

    const int b = blockIdx.y;
    const int h = blockIdx.x;
    const int tid = threadIdx.x;
    const int o_t = tid >> 4;    // 0..15
    const int p_t = tid & 15;    // 0..15

    // load + transpose weights (each thread: 4 float4 rows per matrix)
    #pragma unroll
    for (int i = 0; i < 4; ++i) {
        int o  = (tid >> 4) + 16*i;
        int c0 = (tid & 15)*4;
        float4 w4 = *reinterpret_cast<const float4*>(Wr + o*64 + c0);
        WtA[c0+0][o]=w4.x; WtA[c0+1][o]=w4.y; WtA[c0+2][o]=w4.z; WtA[c0+3][o]=w4.w;
        float4 v4 = *reinterpret_cast<const float4*>(Wv + o*64 + c0);
        WtB[c0+0][o]=v4.x; WtB[c0+1][o]=v4.y; WtB[c0+2][o]=v4.z; WtB[c0+3][o]=v4.w;
    }
    if (tid < 64) {
        float xx = fmaf((float)tid, 2.0f/63.0f, -1.0f);
        gxs[tid] = expf(-2.0f*xx*xx);
    }
    const float yy = fmaf((float)h, 2.0f/63.0f, -1.0f);
    const float gy = expf(-2.0f*yy*yy) * inv_gsum;   // row factor (already * 1/gsum)

    for (int phase = 0; phase < 2; ++phase) {
        const float* Xg = phase ? vis : rubin;
        float (*Wt)[68] = phase ? WtB : WtA;
        __syncthreads();   // protects Xs/red reuse + first-iter LDS init
        // stage raw feature tile [c][w] for image row h (coalesced 256B runs)
        #pragma unroll
        for (int i = 0; i < 4; ++i) {
            int idx = i*1024 + tid*4;
            int c = idx >> 6;
            int w = idx & 63;
            float4 xv = *reinterpret_cast<const float4*>(Xg + (((size_t)b*64 + c)*64 + h)*64 + w);
            *reinterpret_cast<float4*>(&Xs[c][w]) = xv;
        }
        __syncthreads();

        // 64x64 GEMM: rp[o][w] = sum_c W[o][c] * X[c][w]
        float acc[4][4];
        #pragma unroll
        for (int i=0;i<4;++i)
            #pragma unroll
            for (int j=0;j<4;++j) acc[i][j]=0.0f;

        #pragma unroll 4
        for (int c = 0; c < 64; ++c) {
            float4 w4 = *reinterpret_cast<const float4*>(&Wt[c][o_t*4]);
            float4 x4 = *reinterpret_cast<const float4*>(&Xs[c][p_t*4]);
            const float wv[4] = {w4.x,w4.y,w4.z,w4.w};
            const float xv[4] = {x4.x,x4.y,x4.z,x4.w};
            #pragma unroll
            for (int i=0;i<4;++i)
                #pragma unroll
                for (int j=0;j<4;++j)
                    acc[i][j] = fmaf(wv[i], xv[j], acc[i][j]);
        }

        // cross-o_t norm reduction
        #pragma unroll
        for (int j=0;j<4;++j){
            float s = 0.0f;
            #pragma unroll
            for (int i=0;i<4;++i) s = fmaf(acc[i][j], acc[i][j], s);
            red[o_t][p_t*4+j] = s;
        }
        __syncthreads();
        float inv[4], n2[4];
        #pragma unroll
        for (int j=0;j<4;++j){
            float s = 0.0f;
            #pragma unroll
            for (int ot=0;ot<16;++ot) s += red[ot][p_t*4+j];
            n2[j]  = s;
            inv[j] = 1.0f / fmaxf(sqrtf(s), 1e-6f);
        }

        // write normalized field as bf16 [B][C][H][W]
        __hip_bfloat16* Np = phase ? vn : rn;
        #pragma unroll
        for (int i=0;i<4;++i){
            int o = o_t*4+i;
            __hip_bfloat16 hv[4];
            #pragma unroll
            for (int j=0;j<4;++j) hv[j] = __float2bfloat16(acc[i][j]*inv[j]);
            *reinterpret_cast<uint2*>(Np + (((size_t)b*64+o)*64+h)*64 + p_t*4) =
                *reinterpret_cast<uint2*>(hv);
        }

        // gaussian pool of RAW features for this row (tile still in LDS)
        if (tid < 64) {
            int c = tid;
            float s = 0.0f;
            #pragma unroll 4
            for (int p4=0;p4<16;++p4){
                float4 x4 = *reinterpret_cast<const float4*>(&Xs[c][p4*4]);
                int p0 = p4*4;
                s = fmaf(x4.x, gxs[p0+0], s);
                s = fmaf(x4.y, gxs[p0+1], s);
                s = fmaf(x4.z, gxs[p0+2], s);
                s = fmaf(x4.w, gxs[p0+3], s);
            }
            atomicAdd((phase ? v_pool : r_pool) + b*64 + c, s*gy);
        }

        if (phase == 0) {
            // t = energy * gauss ; S = sum(t) over pixels
            if (o_t == 0) {
                float ts = 0.0f;
                #pragma unroll
                for (int j=0;j<4;++j){
                    int w = p_t*4+j;
                    float g  = gxs[w]*gy;
                    float e  = n2[j]*inv[j]*inv[j];
                    float tv = e*g;
                    t_out[(size_t)b*4096 + h*64 + w] = tv;
                    ts += tv;
                }
                redS[p_t] = ts;
            }
            __syncthreads();
            if (tid == 0) {
                float s=0.0f;
                #pragma unroll
                for (int i=0;i<16;++i) s += redS[i];
                atomicAdd(S_out + b, s);
            }
        }
    }
}

// ---------------------------------------------------------------------------
// Kernel B: 49-offset weighted correlation. lane = w (wave64 == image width).
// Each wave: one batch b, band of 4 rubin rows. dx shifts via clamped __shfl,
// one vis-row load serves all (dy,dx) pairings. acc[49] fully unrolled.
// ---------------------------------------------------------------------------
__global__ __launch_bounds__(256) void corr_kernel(
    const __hip_bfloat16* __restrict__ rn, const __hip_bfloat16* __restrict__ vn,
    const float* __restrict__ t_in, const float* __restrict__ S_in,
    float* __restrict__ costs)
{
    const int b    = blockIdx.y;
    const int wv   = threadIdx.x >> 6;
    const int lane = threadIdx.x & 63;
    const int band = blockIdx.x*4 + wv;   // 0..15
    const int h0   = band*4;

    const float invS = 1.0f/(S_in[b] + 1e-8f);
    float swr[4];
    #pragma unroll
    for (int r=0;r<4;++r)
        swr[r] = t_in[(size_t)b*4096 + (h0+r)*64 + lane] * invS;

    int sidx[7];
    #pragma unroll
    for (int d=0;d<7;++d){ int sc = lane + d - 3; sidx[d] = min(max(sc,0),63); }

    float acc[49];
    #pragma unroll
    for (int k=0;k<49;++k) acc[k]=0.0f;

    const size_t base = (size_t)b*64*4096;
    for (int c=0;c<64;++c){
        const size_t cb = base + (size_t)c*4096;
        float ru[4];
        #pragma unroll
        for (int r=0;r<4;++r)
            ru[r] = bf2f(rn[cb + (h0+r)*64 + lane]) * swr[r];
        #pragma unroll
        for (int rv=0; rv<10; ++rv){
            int gr = h0 + rv - 3;
            gr = min(max(gr,0),63);
            float v = bf2f(vn[cb + (size_t)gr*64 + lane]);
            float sh[7];
            #pragma unroll
            for (int d=0;d<7;++d) sh[d] = __shfl(v, sidx[d], 64);
            #pragma unroll
            for (int r=0;r<4;++r){
                const int dyi = rv - r;           // dy+3
                if (dyi >= 0 && dyi <= 6){
                    #pragma unroll
                    for (int d=0;d<7;++d)
                        acc[dyi*7+d] = fmaf(ru[r], sh[d], acc[dyi*7+d]);
                }
            }
        }
    }
    #pragma unroll
    for (int k=0;k<49;++k){
        float s = acc[k];
        #pragma unroll
        for (int off=32; off>=1; off>>=1) s += __shfl_xor(s, off, 64);
        if (lane==0) atomicAdd(costs + b*49 + k, s);
    }
}

// ---------------------------------------------------------------------------
// Kernel C: softmax over 49 costs, coarse shift, feat assembly, MLP (exact
// GELU), finalize. One block (128 threads) per batch.
// ---------------------------------------------------------------------------
__global__ __launch_bounds__(128) void head_kernel(
    const float* __restrict__ costs, const float* __restrict__ r_pool,
    const float* __restrict__ v_pool, const float* __restrict__ p2s,
    const int* __restrict__ band_idx, const float* __restrict__ log_temp,
    const float* __restrict__ band_emb,
    const float* __restrict__ w1, const float* __restrict__ b1,
    const float* __restrict__ w2, const float* __restrict__ b2,
    const float* __restrict__ w3, const float* __restrict__ b3,
    float* __restrict__ out)
{
    __shared__ float feat[210];
    __shared__ float h1s[128];
    __shared__ float h2s[128];
    __shared__ float scal[8];   // cdx, cdy, conf, out0..2
    const int b = blockIdx.x;
    const int tid = threadIdx.x;

    if (tid < 64) {
        float rp = r_pool[b*64+tid], vp = v_pool[b*64+tid];
        feat[tid] = rp; feat[64+tid] = vp; feat[128+tid] = rp - vp;
    }
    if (tid >= 64 && tid < 80) {
        int j = tid - 64;
        feat[194+j] = band_emb[band_idx[b]*16 + j];
    }
    if (tid == 0) {
        float temp  = fmaxf(expf(log_temp[0]), 1e-3f);
        float scale = 1.0f/(8.0f*temp);          // /sqrt(C)/temp
        float lg[49];
        float mx = -1e30f;
        for (int k=0;k<49;++k){ lg[k] = costs[b*49+k]*scale; mx = fmaxf(mx,lg[k]); }
        float se = 0.0f;
        for (int k=0;k<49;++k){ lg[k] = expf(lg[k]-mx); se += lg[k]; }
        float ip = 1.0f/se;
        float cdx=0.0f, cdy=0.0f, cf=0.0f;
        for (int k=0;k<49;++k){
            float p = lg[k]*ip;
            cf  = fmaxf(cf,p);
            cdx += p*(float)((k%7)-3);
            cdy += p*(float)((k/7)-3);
        }
        feat[192]=cdx; feat[193]=cdy;
        scal[0]=cdx; scal[1]=cdy; scal[2]=cf;
    }
    __syncthreads();
    {
        float s = b1[tid];
        for (int i=0;i<210;++i) s = fmaf(feat[i], w1[i*128+tid], s);
        h1s[tid] = geluf(s);
    }
    __syncthreads();
    {
        float s = b2[tid];
        for (int i=0;i<128;++i) s = fmaf(h1s[i], w2[i*128+tid], s);
        h2s[tid] = geluf(s);
    }
    __syncthreads();
    if (tid < 3) {
        float s = b3[tid];
        for (int i=0;i<128;++i) s = fmaf(h2s[i], w3[i*3+tid], s);
        scal[3+tid] = s;
    }
    __syncthreads();
    if (tid == 0) {
        float dx = scal[0] + scal[3];
        float dy = scal[1] + scal[4];
        float ls = fminf(fmaxf(scal[5], -6.0f), 3.0f);
        float sky0 = p2s[b*4+0]*dx + p2s[b*4+1]*dy;
        float sky1 = p2s[b*4+2]*dx + p2s[b*4+3]*dy;
        float* ob = out + b*6;
        ob[0]=dx; ob[1]=dy; ob[2]=sky0; ob[3]=sky1; ob[4]=ls; ob[5]=scal[2];
    }
}

// ---------------------------------------------------------------------------
extern "C" void kernel_launch(void* const* d_in, const int* in_sizes, int n_in,
                              void* d_out, int out_size, void* d_ws, size_t ws_size,
                              hipStream_t stream)
{
    (void)in_sizes; (void)n_in; (void)out_size; (void)ws_size;
    const float* rubin = (const float*)d_in[0];
    const float* vis   = (const float*)d_in[1];
    const float* p2s   = (const float*)d_in[2];
    const int*   bidx  = (const int*)d_in[3];
    const float* Wr    = (const float*)d_in[4];
    const float* Wv    = (const float*)d_in[5];
    const float* ltemp = (const float*)d_in[6];
    const float* bemb  = (const float*)d_in[7];
    const float* w1 = (const float*)d_in[8];
    const float* b1 = (const float*)d_in[9];
    const float* w2 = (const float*)d_in[10];
    const float* b2 = (const float*)d_in[11];
    const float* w3 = (const float*)d_in[12];
    const float* b3 = (const float*)d_in[13];
    float* out = (float*)d_out;

    char* ws = (char*)d_ws;
    const size_t SZ_N = (size_t)128*64*4096*2;           // 64 MiB bf16 field
    __hip_bfloat16* rn = (__hip_bfloat16*)(ws);
    __hip_bfloat16* vn = (__hip_bfloat16*)(ws + SZ_N);
    float* t_buf  = (float*)(ws + 2*SZ_N);               // [128][4096]
    float* S_buf  = (float*)(ws + 2*SZ_N + (size_t)128*4096*4);
    float* rp_buf = S_buf + 128;
    float* vp_buf = rp_buf + 128*64;
    float* co_buf = vp_buf + 128*64;

    // gauss normalizer (host, deterministic per call)
    double gs = 0.0;
    for (int hh=0; hh<64; ++hh) for (int wc=0; wc<64; ++wc){
        double y = -1.0 + hh*(2.0/63.0);
        double x = -1.0 + wc*(2.0/63.0);
        gs += exp(-2.0*(y*y + x*x));
    }
    float inv_gsum = (float)(1.0/gs);

    // zero the atomically-accumulated buffers (S, pools, costs)
    size_t zbytes = (size_t)(128 + 2*128*64 + 128*49)*sizeof(float);
    hipMemsetAsync(S_buf, 0, zbytes, stream);

    proj_kernel<<<dim3(64,128), dim3(256), 0, stream>>>(
        rubin, vis, Wr, Wv, rn, vn, t_buf, S_buf, rp_buf, vp_buf, inv_gsum);
    corr_kernel<<<dim3(4,128), dim3(256), 0, stream>>>(
        rn, vn, t_buf, S_buf, co_buf);
    head_kernel<<<dim3(128), dim3(128), 0, stream>>>(
        co_buf, rp_buf, vp_buf, p2s, bidx, ltemp, bemb, w1, b1, w2, b2, w3, b3, out);
}